// Round 1
// baseline (5651.026 us; speedup 1.0000x reference)
//
#include <hip/hip_runtime.h>
#include <hip/hip_cooperative_groups.h>
#include <math.h>

namespace cg = cooperative_groups;

#define T_ 32
#define B_ 64
#define S_ 64
#define D_ 1024

typedef __attribute__((ext_vector_type(8))) short short8;
typedef __attribute__((ext_vector_type(4))) float floatx4;

__device__ inline short8 ld8s(const short* p){ return *(const short8*)p; }
__device__ inline floatx4 mfma16(short8 a, short8 b, floatx4 c){
  return __builtin_amdgcn_mfma_f32_16x16x32_bf16(a, b, c, 0, 0, 0);
}
__device__ inline float sigm(float x){ return 1.0f/(1.0f+__expf(-x)); }

// ---- fp32 <-> bf16-bits helpers ----
__device__ inline short bfbits(float v){
  unsigned u = __builtin_bit_cast(unsigned, v);
  unsigned r = (u + 0x7FFFu + ((u >> 16) & 1u)) >> 16;   // RNE
  return (short)r;
}
__device__ inline float bitsf(short s){
  unsigned u = ((unsigned)(unsigned short)s) << 16;
  return __builtin_bit_cast(float, u);
}
__device__ inline void split1(float v, short& h, short& l){
  h = bfbits(v); l = bfbits(v - bitsf(h));
}
__device__ inline void pack4(const float4& v, unsigned long long ws_unused,
                             uint2& hp, uint2& lp){
  short h0,h1,h2,h3,l0,l1,l2,l3;
  split1(v.x,h0,l0); split1(v.y,h1,l1); split1(v.z,h2,l2); split1(v.w,h3,l3);
  hp.x = (unsigned short)h0 | ((unsigned)(unsigned short)h1 << 16);
  hp.y = (unsigned short)h2 | ((unsigned)(unsigned short)h3 << 16);
  lp.x = (unsigned short)l0 | ((unsigned)(unsigned short)l1 << 16);
  lp.y = (unsigned short)l2 | ((unsigned)(unsigned short)l3 << 16);
}

// ---------------- generic fp32 -> hi/lo bf16 split ----------------
__global__ __launch_bounds__(256) void split_kernel(const float* __restrict__ src,
                                                    short* __restrict__ hi,
                                                    short* __restrict__ lo){
  int i = blockIdx.x*256 + threadIdx.x;   // one float4 per thread; grid = n/4/256
  float4 v = ((const float4*)src)[i];
  uint2 hp, lp; pack4(v, 0, hp, lp);
  ((uint2*)hi)[i] = hp;
  ((uint2*)lo)[i] = lp;
}

// ---------------- embedding gather + split (padding_idx=0 -> zeros) ----------------
__global__ __launch_bounds__(256) void embed_split(const int* __restrict__ tok,
                                                   const float* __restrict__ emb,
                                                   short* __restrict__ xh,
                                                   short* __restrict__ xl){
  int i = blockIdx.x*256 + threadIdx.x;   // T*B*D/4 = 524288 -> 2048 blocks
  int d4 = i & 255;
  int tb = i >> 8;
  int idx = tok[tb];
  float4 v;
  if (idx == 0) { v.x=v.y=v.z=v.w=0.f; }
  else          { v = ((const float4*)(emb + (size_t)idx*D_))[d4]; }
  uint2 hp, lp; pack4(v, 0, hp, lp);
  ((uint2*)xh)[i] = hp;
  ((uint2*)xl)[i] = lp;
}

// ---------------- LSTM state init: split h0 ----------------
__global__ __launch_bounds__(256) void init_state(const float* __restrict__ h0l,
                                                  short* __restrict__ hh, short* __restrict__ hl){
  int i = blockIdx.x*256 + threadIdx.x;   // B*D/4 = 16384 -> 64 blocks
  float4 v = ((const float4*)h0l)[i];
  uint2 hp, lp; pack4(v, 0, hp, lp);
  ((uint2*)hh)[i] = hp;
  ((uint2*)hl)[i] = lp;
}

// ---- GEMM on pre-split operands: C = act( A1@B1^T [+ A2@B2^T] [+ bias] ) ----
// A,B stored as separate hi/lo bf16(short) arrays, K-contiguous rows.
// block = 4 waves; wave w: rows [by*64+w*16,+16) x cols [bx*64,+64)
__global__ __launch_bounds__(256) void gemm_hl(
    const short* __restrict__ A1h, const short* __restrict__ A1l, int lda1,
    const short* __restrict__ B1h, const short* __restrict__ B1l, int ldb1, int K1,
    const short* __restrict__ A2h, const short* __restrict__ A2l, int lda2,
    const short* __restrict__ B2h, const short* __restrict__ B2l, int ldb2, int K2,
    const float* __restrict__ bias0, const float* __restrict__ bias1,
    float* __restrict__ Cf, short* __restrict__ Ch, short* __restrict__ Cl,
    int ldc, int act)
{
  int wave = threadIdx.x >> 6;
  int lane = threadIdx.x & 63;
  int lr = lane & 15;
  int lk = (lane >> 4) * 8;
  int m0 = blockIdx.y*64 + wave*16;
  int n0 = blockIdx.x*64;
  floatx4 acc[4] = {};
  {
    const short* ah = A1h + (size_t)(m0 + lr)*lda1 + lk;
    const short* al = A1l + (size_t)(m0 + lr)*lda1 + lk;
    for (int k0 = 0; k0 < K1; k0 += 32) {
      short8 vh = ld8s(ah + k0);
      short8 vl = ld8s(al + k0);
#pragma unroll
      for (int nt = 0; nt < 4; ++nt) {
        size_t bo = (size_t)(n0 + nt*16 + lr)*ldb1 + k0 + lk;
        short8 bh = ld8s(B1h + bo);
        short8 bl = ld8s(B1l + bo);
        acc[nt] = mfma16(vl, bh, acc[nt]);
        acc[nt] = mfma16(vh, bl, acc[nt]);
        acc[nt] = mfma16(vh, bh, acc[nt]);
      }
    }
  }
  if (A2h) {
    const short* ah = A2h + (size_t)(m0 + lr)*lda2 + lk;
    const short* al = A2l + (size_t)(m0 + lr)*lda2 + lk;
    for (int k0 = 0; k0 < K2; k0 += 32) {
      short8 vh = ld8s(ah + k0);
      short8 vl = ld8s(al + k0);
#pragma unroll
      for (int nt = 0; nt < 4; ++nt) {
        size_t bo = (size_t)(n0 + nt*16 + lr)*ldb2 + k0 + lk;
        short8 bh = ld8s(B2h + bo);
        short8 bl = ld8s(B2l + bo);
        acc[nt] = mfma16(vl, bh, acc[nt]);
        acc[nt] = mfma16(vh, bl, acc[nt]);
        acc[nt] = mfma16(vh, bh, acc[nt]);
      }
    }
  }
  int rb = (lane >> 4) * 4;
#pragma unroll
  for (int nt = 0; nt < 4; ++nt) {
    int col = n0 + nt*16 + lr;
    float badd = bias0 ? (bias0[col] + bias1[col]) : 0.f;
#pragma unroll
    for (int r = 0; r < 4; ++r) {
      size_t idx = (size_t)(m0 + rb + r)*ldc + col;
      float v = acc[nt][r] + badd;
      if (act) v = tanhf(v);
      if (Cf) Cf[idx] = v;
      else { short h,l; split1(v,h,l); Ch[idx] = h; Cl[idx] = l; }
    }
  }
}

// ---- whole-layer LSTM recurrence: one cooperative launch, T=32 internal steps ----
// grid = 256 blocks x 256 threads (1 block/CU). Block j owns gate rows [16j,16j+16).
// whh slice (hi+lo, 64 KB) staged to LDS once (XOR-swizzled, G4 bank fix), reused
// for all timesteps. Per step: GEMM phase -> grid.sync -> elementwise -> grid.sync.
// c state lives in a register per thread for the entire sequence.
__global__ __launch_bounds__(256) void lstm_seq(
    const float* __restrict__ xg,                       // (T,B,4D) fp32, bias folded
    const short* __restrict__ whh_h, const short* __restrict__ whh_l,
    short* __restrict__ hbh, short* __restrict__ hbl,   // ping-pong (2*B*D each)
    const float* __restrict__ cinit,                    // c0 layer slice (B,D)
    float* __restrict__ gates,                          // (B,4D) fp32 scratch
    short* __restrict__ xoh, short* __restrict__ xol,   // (T,B,D) layer output
    float* __restrict__ hn_out, float* __restrict__ cn_out)
{
  cg::grid_group grid = cg::this_grid();
  __shared__ short8 whv_h[16*128];   // 32 KB
  __shared__ short8 whv_l[16*128];   // 32 KB
  const int j    = blockIdx.x;       // gate-row tile 0..255
  const int tid  = threadIdx.x;
  const int wave = tid >> 6;
  const int lane = tid & 63;
  const int lr   = lane & 15;
  const int qo   = lane >> 4;        // K-subchunk 0..3 (8 shorts each)
  const int rb   = qo * 4;

  // stage whh rows [16j,16j+16) hi+lo into LDS, chunk-XOR swizzle per row
  {
    const short8* srcH = (const short8*)(whh_h + (size_t)j*16*D_);
    const short8* srcL = (const short8*)(whh_l + (size_t)j*16*D_);
    for (int c = tid; c < 2048; c += 256) {
      int row = c >> 7, cc = c & 127;
      int di = row*128 + (cc ^ (row & 7));
      whv_h[di] = srcH[c];
      whv_l[di] = srcL[c];
    }
  }
  // elementwise mapping: thread p -> (b,d); c kept in register
  const int p = j*256 + tid;
  const int b = p >> 10, d = p & 1023;
  float creg = cinit[p];
  __syncthreads();

  const int bswz = lr*128;
  const int bx   = lr & 7;

  for (int t = 0; t < T_; ++t) {
    // ---- GEMM phase: gates[0:64][16j:16j+16] = h_t @ whh_slice^T ----
    const short* hih = hbh + (size_t)(t & 1)*(B_*D_);
    const short* hil = hbl + (size_t)(t & 1)*(B_*D_);
    const short8* ah8 = (const short8*)(hih + (size_t)(wave*16 + lr)*D_);
    const short8* al8 = (const short8*)(hil + (size_t)(wave*16 + lr)*D_);
    floatx4 acc = {};
#pragma unroll 4
    for (int kc = 0; kc < 32; ++kc) {
      int cc = kc*4 + qo;
      short8 ahv = ah8[cc];
      short8 alv = al8[cc];
      int bi = bswz + (cc ^ bx);
      short8 bhv = whv_h[bi];
      short8 blv = whv_l[bi];
      acc = mfma16(alv, bhv, acc);
      acc = mfma16(ahv, blv, acc);
      acc = mfma16(ahv, bhv, acc);
    }
#pragma unroll
    for (int r = 0; r < 4; ++r)
      gates[(size_t)(wave*16 + rb + r)*(4*D_) + j*16 + lr] = acc[r];
    grid.sync();

    // ---- elementwise phase: 1 element per thread ----
    {
      size_t gb = (size_t)b*(4*D_) + d;
      size_t xb = ((size_t)t*B_ + b)*(4*D_) + d;
      float i_ = sigm (gates[gb        ] + xg[xb        ]);
      float f_ = sigm (gates[gb +   D_ ] + xg[xb +   D_ ]);
      float gg = tanhf(gates[gb + 2*D_ ] + xg[xb + 2*D_ ]);
      float o_ = sigm (gates[gb + 3*D_ ] + xg[xb + 3*D_ ]);
      creg = f_*creg + i_*gg;
      float h = o_*tanhf(creg);
      short hh, hl; split1(h, hh, hl);
      short* nh = hbh + (size_t)((t+1) & 1)*(B_*D_);
      short* nl = hbl + (size_t)((t+1) & 1)*(B_*D_);
      nh[p] = hh; nl[p] = hl;
      size_t xi = ((size_t)t*B_ + b)*D_ + d;
      xoh[xi] = hh; xol[xi] = hl;
      if (t == T_-1) { hn_out[p] = h; cn_out[p] = creg; }
    }
    grid.sync();
  }
}

// ---------------- attention: one block per batch b ----------------
__global__ __launch_bounds__(256) void attn2(
    const short* __restrict__ qh, const short* __restrict__ ql,   // (T,B,D)
    const short* __restrict__ cxh, const short* __restrict__ cxl, // (S,B,D)
    short* __restrict__ wth, short* __restrict__ wtl,             // (T,B,D)
    float* __restrict__ attn_out)                                 // (B,S) at t=T-1
{
  int b = blockIdx.x;
  __shared__ float sc[32][64];
  __shared__ short at_hi[32][64];
  __shared__ short at_lo[32][64];
  int wave = threadIdx.x >> 6;
  int lane = threadIdx.x & 63;
  int lr = lane & 15;
  int lk = (lane >> 4) * 8;
  int rb = (lane >> 4) * 4;

  // phase 1: scores(32,64) = Q_b(32,1024) @ CtxB(64,1024)^T
  {
    floatx4 acc[2] = {};
    int n0 = wave * 16;
    size_t Bo = ((size_t)(n0 + lr)*B_ + b)*D_ + lk;
    size_t A0 = ((size_t)(0  + lr)*B_ + b)*D_ + lk;
    size_t A1 = ((size_t)(16 + lr)*B_ + b)*D_ + lk;
    for (int k0 = 0; k0 < D_; k0 += 32) {
      short8 bh = ld8s(cxh + Bo + k0);
      short8 bl = ld8s(cxl + Bo + k0);
      short8 a0h = ld8s(qh + A0 + k0), a0l = ld8s(ql + A0 + k0);
      acc[0] = mfma16(a0l, bh, acc[0]);
      acc[0] = mfma16(a0h, bl, acc[0]);
      acc[0] = mfma16(a0h, bh, acc[0]);
      short8 a1h = ld8s(qh + A1 + k0), a1l = ld8s(ql + A1 + k0);
      acc[1] = mfma16(a1l, bh, acc[1]);
      acc[1] = mfma16(a1h, bl, acc[1]);
      acc[1] = mfma16(a1h, bh, acc[1]);
    }
#pragma unroll
    for (int m = 0; m < 2; ++m)
#pragma unroll
      for (int r = 0; r < 4; ++r)
        sc[m*16 + rb + r][n0 + lr] = acc[m][r];
  }
  __syncthreads();

  // softmax over s; threads 0..31 each own one t
  if (threadIdx.x < 32) {
    int t = threadIdx.x;
    float mx = -1e30f;
    for (int s = 0; s < 64; ++s) mx = fmaxf(mx, sc[t][s]);
    float sum = 0.f;
    for (int s = 0; s < 64; ++s) { float v = __expf(sc[t][s] - mx); sum += v; sc[t][s] = v; }
    float inv = 1.f / sum;
    for (int s = 0; s < 64; ++s) {
      float v = sc[t][s] * inv;
      short h, l; split1(v, h, l);
      at_hi[t][s] = h; at_lo[t][s] = l;
      if (t == 31) attn_out[b*64 + s] = v;
    }
  }
  __syncthreads();

  // phase 2: weighted(32,1024) = attn(32,64) @ CtxB(64,1024)
  for (int i = 0; i < 16; ++i) {
    int n0 = (wave + 4*i) * 16;
    floatx4 acc[2] = {};
#pragma unroll
    for (int kk = 0; kk < 2; ++kk) {
      short8 bh, bl;
#pragma unroll
      for (int j = 0; j < 8; ++j) {
        int s = kk*32 + (lane >> 4)*8 + j;
        size_t o = ((size_t)s*B_ + b)*D_ + n0 + lr;
        bh[j] = cxh[o];
        bl[j] = cxl[o];
      }
      short8 a0h = *(const short8*)&at_hi[0  + lr][kk*32 + lk];
      short8 a0l = *(const short8*)&at_lo[0  + lr][kk*32 + lk];
      short8 a1h = *(const short8*)&at_hi[16 + lr][kk*32 + lk];
      short8 a1l = *(const short8*)&at_lo[16 + lr][kk*32 + lk];
      acc[0] = mfma16(a0l, bh, acc[0]);
      acc[0] = mfma16(a0h, bl, acc[0]);
      acc[0] = mfma16(a0h, bh, acc[0]);
      acc[1] = mfma16(a1l, bh, acc[1]);
      acc[1] = mfma16(a1h, bl, acc[1]);
      acc[1] = mfma16(a1h, bh, acc[1]);
    }
#pragma unroll
    for (int m = 0; m < 2; ++m)
#pragma unroll
      for (int r = 0; r < 4; ++r) {
        int t = m*16 + rb + r;
        size_t oi = ((size_t)t*B_ + b)*D_ + n0 + lr;
        float v = acc[m][r];
        short h, l; split1(v, h, l);
        wth[oi] = h; wtl[oi] = l;
      }
  }
}

extern "C" void kernel_launch(void* const* d_in, const int* in_sizes, int n_in,
                              void* d_out, int out_size, void* d_ws, size_t ws_size,
                              hipStream_t stream) {
  const int*   tok   = (const int*)  d_in[0];
  const float* h0    = (const float*)d_in[1];
  const float* c0    = (const float*)d_in[2];
  const float* ctx   = (const float*)d_in[3];
  const float* emb   = (const float*)d_in[5];
  const float* wih[2] = {(const float*)d_in[6],  (const float*)d_in[10]};
  const float* whh[2] = {(const float*)d_in[7],  (const float*)d_in[11]};
  const float* bih[2] = {(const float*)d_in[8],  (const float*)d_in[12]};
  const float* bhh[2] = {(const float*)d_in[9],  (const float*)d_in[13]};
  const float* w_in  = (const float*)d_in[14];
  const float* w_out = (const float*)d_in[15];
  float* outp = (float*)d_out;

  // ---- workspace layout (88.75 MB) ----
  char* ws = (char*)d_ws;
#define MB(x) ((size_t)(x) << 20)
  short* x0h = (short*)(ws + MB(0));    // 4 MB each (T*B*D shorts)
  short* x0l = (short*)(ws + MB(4));
  short* x1h = (short*)(ws + MB(8));
  short* x1l = (short*)(ws + MB(12));
  short* x2h = (short*)(ws + MB(16));
  short* x2l = (short*)(ws + MB(20));
  float* xg  = (float*)(ws + MB(24));   // 32 MB fp32 (T,B,4D)
  short* wihh = (short*)(ws + MB(56));  // 8 MB (4D*D shorts)
  short* wihl = (short*)(ws + MB(64));  // 8 MB
  short* whhh = (short*)(ws + MB(72));  // 8 MB
  short* whhl = (short*)(ws + MB(80));  // 8 MB
  // overlays (lifetimes disjoint):
  float* gates = (float*)(ws + MB(56)); // 1 MB gate scratch (over wih split buf,
                                        // dead between big-gemm and next split)
  short* q_h  = x0h;                    // q hi/lo over x0 (dead after layer0 xg)
  short* q_l  = x0l;
  short* wt_h = x1h;                    // weighted hi/lo over x1 (dead after layer1 xg)
  short* wt_l = x1l;
  short* winh = (short*)(ws + MB(56));  // w_in hi/lo over wih buf (2 MB each)
  short* winl = (short*)(ws + MB(58));
  short* wouth = (short*)(ws + MB(60)); // w_out hi/lo (4 MB each)
  short* woutl = (short*)(ws + MB(64));
  short* cxh = (short*)(ws + MB(72));   // ctx hi/lo over whh buf (8 MB each)
  short* cxl = (short*)(ws + MB(80));
  short* hbh  = (short*)(ws + MB(88) + 262144);     // 2 x 128 KB ping-pong hi
  short* hbl  = (short*)(ws + MB(88) + 524288);     // 2 x 128 KB ping-pong lo
#undef MB

  const size_t BD = (size_t)B_*D_;
  const size_t OUT_HN   = (size_t)T_*B_*D_;   // 2097152
  const size_t OUT_CN   = OUT_HN + 2*BD;
  const size_t OUT_ATTN = OUT_CN + 2*BD;

  embed_split<<<2048, 256, 0, stream>>>(tok, emb, x0h, x0l);

  for (int l = 0; l < 2; ++l) {
    const short* xinh = l ? x1h : x0h;
    const short* xinl = l ? x1l : x0l;
    short* xoh = l ? x2h : x1h;
    short* xol = l ? x2l : x1l;
    // split this layer's weights
    split_kernel<<<4096, 256, 0, stream>>>(wih[l], wihh, wihl);
    // xg = x @ wih^T + (bih+bhh)  : M=2048, N=4096, K=1024, fp32 out
    gemm_hl<<<dim3(64, 32), 256, 0, stream>>>(
        xinh, xinl, D_, wihh, wihl, D_, D_,
        nullptr, nullptr, 0, nullptr, nullptr, 0, 0,
        bih[l], bhh[l], xg, nullptr, nullptr, 4*D_, 0);
    split_kernel<<<4096, 256, 0, stream>>>(whh[l], whhh, whhl);
    init_state<<<64, 256, 0, stream>>>(h0 + (size_t)l*BD, hbh, hbl);
    // whole recurrence in one cooperative launch
    {
      const float* c0l = c0 + (size_t)l*BD;
      float* hn = outp + OUT_HN + (size_t)l*BD;
      float* cn = outp + OUT_CN + (size_t)l*BD;
      float* xg_p = xg;
      const short* whhh_c = whhh;
      const short* whhl_c = whhl;
      short* hbh_p = hbh;
      short* hbl_p = hbl;
      short* xoh_p = xoh;
      short* xol_p = xol;
      void* kargs[] = {
        (void*)&xg_p, (void*)&whhh_c, (void*)&whhl_c,
        (void*)&hbh_p, (void*)&hbl_p, (void*)&c0l, (void*)&gates,
        (void*)&xoh_p, (void*)&xol_p, (void*)&hn, (void*)&cn
      };
      hipLaunchCooperativeKernel((const void*)lstm_seq, dim3(256), dim3(256),
                                 kargs, 0, stream);
    }
  }

  // split attention/projection weights (overlay wih/whh buffers, now dead)
  split_kernel<<<1024, 256, 0, stream>>>(w_in,  winh,  winl);
  split_kernel<<<2048, 256, 0, stream>>>(w_out, wouth, woutl);
  // q = x2 @ w_in^T -> hi/lo (over x0)
  gemm_hl<<<dim3(16, 32), 256, 0, stream>>>(
      x2h, x2l, D_, winh, winl, D_, D_,
      nullptr, nullptr, 0, nullptr, nullptr, 0, 0,
      nullptr, nullptr, nullptr, q_h, q_l, D_, 0);
  split_kernel<<<4096, 256, 0, stream>>>(ctx, cxh, cxl);
  attn2<<<64, 256, 0, stream>>>(q_h, q_l, cxh, cxl, wt_h, wt_l, outp + OUT_ATTN);
  // out = tanh( wt@w_out[:, :D]^T + x2@w_out[:, D:]^T ) -> fp32
  gemm_hl<<<dim3(16, 32), 256, 0, stream>>>(
      wt_h, wt_l, D_, wouth, woutl, 2*D_, D_,
      x2h, x2l, D_, wouth + D_, woutl + D_, 2*D_, D_,
      nullptr, nullptr, outp, nullptr, nullptr, D_, 1);
}

// Round 2
// 2033.829 us; speedup vs baseline: 2.7785x; 2.7785x over previous
//
#include <hip/hip_runtime.h>
#include <math.h>

#define T_ 32
#define B_ 64
#define S_ 64
#define D_ 1024

typedef __attribute__((ext_vector_type(8))) short short8;
typedef __attribute__((ext_vector_type(4))) float floatx4;

__device__ inline short8 ld8s(const short* p){ return *(const short8*)p; }
__device__ inline floatx4 mfma16(short8 a, short8 b, floatx4 c){
  return __builtin_amdgcn_mfma_f32_16x16x32_bf16(a, b, c, 0, 0, 0);
}
__device__ inline float sigm(float x){ return 1.0f/(1.0f+__expf(-x)); }

// ---- fp32 <-> bf16-bits helpers ----
__device__ inline short bfbits(float v){
  unsigned u = __builtin_bit_cast(unsigned, v);
  unsigned r = (u + 0x7FFFu + ((u >> 16) & 1u)) >> 16;   // RNE
  return (short)r;
}
__device__ inline float bitsf(short s){
  unsigned u = ((unsigned)(unsigned short)s) << 16;
  return __builtin_bit_cast(float, u);
}
__device__ inline void split1(float v, short& h, short& l){
  h = bfbits(v); l = bfbits(v - bitsf(h));
}
__device__ inline void pack4(const float4& v, unsigned long long ws_unused,
                             uint2& hp, uint2& lp){
  short h0,h1,h2,h3,l0,l1,l2,l3;
  split1(v.x,h0,l0); split1(v.y,h1,l1); split1(v.z,h2,l2); split1(v.w,h3,l3);
  hp.x = (unsigned short)h0 | ((unsigned)(unsigned short)h1 << 16);
  hp.y = (unsigned short)h2 | ((unsigned)(unsigned short)h3 << 16);
  lp.x = (unsigned short)l0 | ((unsigned)(unsigned short)l1 << 16);
  lp.y = (unsigned short)l2 | ((unsigned)(unsigned short)l3 << 16);
}

// ---------------- generic fp32 -> hi/lo bf16 split ----------------
__global__ __launch_bounds__(256) void split_kernel(const float* __restrict__ src,
                                                    short* __restrict__ hi,
                                                    short* __restrict__ lo){
  int i = blockIdx.x*256 + threadIdx.x;   // one float4 per thread; grid = n/4/256
  float4 v = ((const float4*)src)[i];
  uint2 hp, lp; pack4(v, 0, hp, lp);
  ((uint2*)hi)[i] = hp;
  ((uint2*)lo)[i] = lp;
}

// ---- whh split + row permutation: orig row g*D + d  ->  new row (d>>2)*16 + g*4 + (d&3)
// so block j of the step kernel owns contiguous rows [16j, 16j+16) covering all 4 gates
// for its 4 d-values.
__global__ __launch_bounds__(256) void split_whh(const float* __restrict__ src,
                                                 short* __restrict__ hi,
                                                 short* __restrict__ lo){
  int i = blockIdx.x*256 + threadIdx.x;   // 4D*D/4 float4 elems -> 4096 blocks
  int row = i >> 8, c4 = i & 255;         // D/4 = 256 float4 per row
  int g = row >> 10, d = row & 1023;
  int nrow = ((d >> 2) << 4) + (g << 2) + (d & 3);
  float4 v = ((const float4*)src)[i];
  uint2 hp, lp; pack4(v, 0, hp, lp);
  int o = nrow*256 + c4;
  ((uint2*)hi)[o] = hp;
  ((uint2*)lo)[o] = lp;
}

// ---------------- embedding gather + split (padding_idx=0 -> zeros) ----------------
__global__ __launch_bounds__(256) void embed_split(const int* __restrict__ tok,
                                                   const float* __restrict__ emb,
                                                   short* __restrict__ xh,
                                                   short* __restrict__ xl){
  int i = blockIdx.x*256 + threadIdx.x;   // T*B*D/4 = 524288 -> 2048 blocks
  int d4 = i & 255;
  int tb = i >> 8;
  int idx = tok[tb];
  float4 v;
  if (idx == 0) { v.x=v.y=v.z=v.w=0.f; }
  else          { v = ((const float4*)(emb + (size_t)idx*D_))[d4]; }
  uint2 hp, lp; pack4(v, 0, hp, lp);
  ((uint2*)xh)[i] = hp;
  ((uint2*)xl)[i] = lp;
}

// ---------------- LSTM state init: split h0, copy c0 ----------------
__global__ __launch_bounds__(256) void init_state(const float* __restrict__ h0l,
                                                  const float* __restrict__ c0l,
                                                  short* __restrict__ hh, short* __restrict__ hl,
                                                  float* __restrict__ c){
  int i = blockIdx.x*256 + threadIdx.x;   // B*D/4 = 16384 -> 64 blocks
  float4 v = ((const float4*)h0l)[i];
  uint2 hp, lp; pack4(v, 0, hp, lp);
  ((uint2*)hh)[i] = hp;
  ((uint2*)hl)[i] = lp;
  ((float4*)c)[i] = ((const float4*)c0l)[i];
}

// ---- GEMM on pre-split operands: C = act( A1@B1^T [+ A2@B2^T] [+ bias] ) ----
// A,B stored as separate hi/lo bf16(short) arrays, K-contiguous rows.
// block = 4 waves; wave w: rows [by*64+w*16,+16) x cols [bx*64,+64)
__global__ __launch_bounds__(256) void gemm_hl(
    const short* __restrict__ A1h, const short* __restrict__ A1l, int lda1,
    const short* __restrict__ B1h, const short* __restrict__ B1l, int ldb1, int K1,
    const short* __restrict__ A2h, const short* __restrict__ A2l, int lda2,
    const short* __restrict__ B2h, const short* __restrict__ B2l, int ldb2, int K2,
    const float* __restrict__ bias0, const float* __restrict__ bias1,
    float* __restrict__ Cf, short* __restrict__ Ch, short* __restrict__ Cl,
    int ldc, int act)
{
  int wave = threadIdx.x >> 6;
  int lane = threadIdx.x & 63;
  int lr = lane & 15;
  int lk = (lane >> 4) * 8;
  int m0 = blockIdx.y*64 + wave*16;
  int n0 = blockIdx.x*64;
  floatx4 acc[4] = {};
  {
    const short* ah = A1h + (size_t)(m0 + lr)*lda1 + lk;
    const short* al = A1l + (size_t)(m0 + lr)*lda1 + lk;
    for (int k0 = 0; k0 < K1; k0 += 32) {
      short8 vh = ld8s(ah + k0);
      short8 vl = ld8s(al + k0);
#pragma unroll
      for (int nt = 0; nt < 4; ++nt) {
        size_t bo = (size_t)(n0 + nt*16 + lr)*ldb1 + k0 + lk;
        short8 bh = ld8s(B1h + bo);
        short8 bl = ld8s(B1l + bo);
        acc[nt] = mfma16(vl, bh, acc[nt]);
        acc[nt] = mfma16(vh, bl, acc[nt]);
        acc[nt] = mfma16(vh, bh, acc[nt]);
      }
    }
  }
  if (A2h) {
    const short* ah = A2h + (size_t)(m0 + lr)*lda2 + lk;
    const short* al = A2l + (size_t)(m0 + lr)*lda2 + lk;
    for (int k0 = 0; k0 < K2; k0 += 32) {
      short8 vh = ld8s(ah + k0);
      short8 vl = ld8s(al + k0);
#pragma unroll
      for (int nt = 0; nt < 4; ++nt) {
        size_t bo = (size_t)(n0 + nt*16 + lr)*ldb2 + k0 + lk;
        short8 bh = ld8s(B2h + bo);
        short8 bl = ld8s(B2l + bo);
        acc[nt] = mfma16(vl, bh, acc[nt]);
        acc[nt] = mfma16(vh, bl, acc[nt]);
        acc[nt] = mfma16(vh, bh, acc[nt]);
      }
    }
  }
  int rb = (lane >> 4) * 4;
#pragma unroll
  for (int nt = 0; nt < 4; ++nt) {
    int col = n0 + nt*16 + lr;
    float badd = bias0 ? (bias0[col] + bias1[col]) : 0.f;
#pragma unroll
    for (int r = 0; r < 4; ++r) {
      size_t idx = (size_t)(m0 + rb + r)*ldc + col;
      float v = acc[nt][r] + badd;
      if (act) v = tanhf(v);
      if (Cf) Cf[idx] = v;
      else { short h,l; split1(v,h,l); Ch[idx] = h; Cl[idx] = l; }
    }
  }
}

// ---- one LSTM timestep, fully fused, self-contained per block ----
// grid = 256 blocks x 512 threads (8 waves). Block j owns the 16 permuted whh rows
// [16j,16j+16) = {gate g, d = 4j+u}. Waves 0-3: batch tiles x K[0,512);
// waves 4-7: batch tiles x K[512,1024). Weight slice staged in swizzled LDS once,
// reused by all 8 waves. Elementwise for d in [4j,4j+4) x 64 batches is block-local.
__global__ __launch_bounds__(512) void lstm_step3(
    const float* __restrict__ xg, int t,
    const short* __restrict__ whr_h, const short* __restrict__ whr_l, // permuted rows
    const short* __restrict__ hih, const short* __restrict__ hil,
    float* __restrict__ c,
    short* __restrict__ hoh, short* __restrict__ hol,
    short* __restrict__ xoh, short* __restrict__ xol,
    float* __restrict__ hn_out, float* __restrict__ cn_out)
{
  __shared__ short8 wv_h[16*128];       // 32 KB, row-chunk XOR swizzled
  __shared__ short8 wv_l[16*128];       // 32 KB
  __shared__ float g_lds[2][64][17];    // 8.5 KB (pad 17 vs bank conflicts)
  const int j    = blockIdx.x;
  const int tid  = threadIdx.x;
  const int wave = tid >> 6;
  const int lane = tid & 63;
  const int lr   = lane & 15;
  const int qo   = lane >> 4;

  // stage 16 weight rows (hi+lo) into LDS with chunk XOR swizzle
  {
    const short8* srcH = (const short8*)(whr_h + (size_t)j*16*D_);
    const short8* srcL = (const short8*)(whr_l + (size_t)j*16*D_);
#pragma unroll
    for (int it = 0; it < 4; ++it) {
      int p = it*512 + tid;             // physical LDS chunk
      int row = p >> 7, pc = p & 127;
      int cc = pc ^ (row & 7);          // logical chunk stored at p
      wv_h[p] = srcH[row*128 + cc];
      wv_l[p] = srcL[row*128 + cc];
    }
  }
  __syncthreads();

  // GEMM: wave = (batch tile bt, K half kh)
  const int bt = (wave & 3) * 16;
  const int kh = wave >> 2;
  const short8* ah8 = (const short8*)(hih + (size_t)(bt + lr)*D_);
  const short8* al8 = (const short8*)(hil + (size_t)(bt + lr)*D_);
  const int bswz = lr*128;
  const int bx   = lr & 7;
  floatx4 acc = {};
#pragma unroll 4
  for (int kc = kh*16; kc < kh*16 + 16; ++kc) {
    int cc = kc*4 + qo;
    short8 ahv = ah8[cc];
    short8 alv = al8[cc];
    int bi = bswz + (cc ^ bx);
    short8 bhv = wv_h[bi];
    short8 blv = wv_l[bi];
    acc = mfma16(alv, bhv, acc);
    acc = mfma16(ahv, blv, acc);
    acc = mfma16(ahv, bhv, acc);
  }
  // C layout: lane holds C[batch = bt + qo*4 + r][gaterow = lr]
  int rb = qo*4;
#pragma unroll
  for (int r = 0; r < 4; ++r)
    g_lds[kh][bt + rb + r][lr] = acc[r];
  __syncthreads();

  // elementwise: 256 elements (64 b x 4 u), threads 0..255
  if (tid < 256) {
    int b = tid >> 2, u = tid & 3;
    int d = j*4 + u;
    size_t xb = ((size_t)t*B_ + b)*(4*D_) + d;
    float i_ = sigm (g_lds[0][b][0*4+u] + g_lds[1][b][0*4+u] + xg[xb        ]);
    float f_ = sigm (g_lds[0][b][1*4+u] + g_lds[1][b][1*4+u] + xg[xb +   D_ ]);
    float gg = tanhf(g_lds[0][b][2*4+u] + g_lds[1][b][2*4+u] + xg[xb + 2*D_]);
    float o_ = sigm (g_lds[0][b][3*4+u] + g_lds[1][b][3*4+u] + xg[xb + 3*D_]);
    size_t ci = (size_t)b*D_ + d;
    float cn = f_*c[ci] + i_*gg;
    c[ci] = cn;
    float h = o_*tanhf(cn);
    short hh, hl; split1(h, hh, hl);
    hoh[ci] = hh; hol[ci] = hl;
    size_t xi = ((size_t)t*B_ + b)*D_ + d;
    xoh[xi] = hh; xol[xi] = hl;
    if (hn_out) { hn_out[ci] = h; cn_out[ci] = cn; }
  }
}

// ---------------- attention: one block per batch b ----------------
__global__ __launch_bounds__(256) void attn2(
    const short* __restrict__ qh, const short* __restrict__ ql,   // (T,B,D)
    const short* __restrict__ cxh, const short* __restrict__ cxl, // (S,B,D)
    short* __restrict__ wth, short* __restrict__ wtl,             // (T,B,D)
    float* __restrict__ attn_out)                                 // (B,S) at t=T-1
{
  int b = blockIdx.x;
  __shared__ float sc[32][64];
  __shared__ short at_hi[32][64];
  __shared__ short at_lo[32][64];
  int wave = threadIdx.x >> 6;
  int lane = threadIdx.x & 63;
  int lr = lane & 15;
  int lk = (lane >> 4) * 8;
  int rb = (lane >> 4) * 4;

  // phase 1: scores(32,64) = Q_b(32,1024) @ CtxB(64,1024)^T
  {
    floatx4 acc[2] = {};
    int n0 = wave * 16;
    size_t Bo = ((size_t)(n0 + lr)*B_ + b)*D_ + lk;
    size_t A0 = ((size_t)(0  + lr)*B_ + b)*D_ + lk;
    size_t A1 = ((size_t)(16 + lr)*B_ + b)*D_ + lk;
    for (int k0 = 0; k0 < D_; k0 += 32) {
      short8 bh = ld8s(cxh + Bo + k0);
      short8 bl = ld8s(cxl + Bo + k0);
      short8 a0h = ld8s(qh + A0 + k0), a0l = ld8s(ql + A0 + k0);
      acc[0] = mfma16(a0l, bh, acc[0]);
      acc[0] = mfma16(a0h, bl, acc[0]);
      acc[0] = mfma16(a0h, bh, acc[0]);
      short8 a1h = ld8s(qh + A1 + k0), a1l = ld8s(ql + A1 + k0);
      acc[1] = mfma16(a1l, bh, acc[1]);
      acc[1] = mfma16(a1h, bl, acc[1]);
      acc[1] = mfma16(a1h, bh, acc[1]);
    }
#pragma unroll
    for (int m = 0; m < 2; ++m)
#pragma unroll
      for (int r = 0; r < 4; ++r)
        sc[m*16 + rb + r][n0 + lr] = acc[m][r];
  }
  __syncthreads();

  // softmax over s; threads 0..31 each own one t
  if (threadIdx.x < 32) {
    int t = threadIdx.x;
    float mx = -1e30f;
    for (int s = 0; s < 64; ++s) mx = fmaxf(mx, sc[t][s]);
    float sum = 0.f;
    for (int s = 0; s < 64; ++s) { float v = __expf(sc[t][s] - mx); sum += v; sc[t][s] = v; }
    float inv = 1.f / sum;
    for (int s = 0; s < 64; ++s) {
      float v = sc[t][s] * inv;
      short h, l; split1(v, h, l);
      at_hi[t][s] = h; at_lo[t][s] = l;
      if (t == 31) attn_out[b*64 + s] = v;
    }
  }
  __syncthreads();

  // phase 2: weighted(32,1024) = attn(32,64) @ CtxB(64,1024)
  for (int i = 0; i < 16; ++i) {
    int n0 = (wave + 4*i) * 16;
    floatx4 acc[2] = {};
#pragma unroll
    for (int kk = 0; kk < 2; ++kk) {
      short8 bh, bl;
#pragma unroll
      for (int j = 0; j < 8; ++j) {
        int s = kk*32 + (lane >> 4)*8 + j;
        size_t o = ((size_t)s*B_ + b)*D_ + n0 + lr;
        bh[j] = cxh[o];
        bl[j] = cxl[o];
      }
      short8 a0h = *(const short8*)&at_hi[0  + lr][kk*32 + lk];
      short8 a0l = *(const short8*)&at_lo[0  + lr][kk*32 + lk];
      short8 a1h = *(const short8*)&at_hi[16 + lr][kk*32 + lk];
      short8 a1l = *(const short8*)&at_lo[16 + lr][kk*32 + lk];
      acc[0] = mfma16(a0l, bh, acc[0]);
      acc[0] = mfma16(a0h, bl, acc[0]);
      acc[0] = mfma16(a0h, bh, acc[0]);
      acc[1] = mfma16(a1l, bh, acc[1]);
      acc[1] = mfma16(a1h, bl, acc[1]);
      acc[1] = mfma16(a1h, bh, acc[1]);
    }
#pragma unroll
    for (int m = 0; m < 2; ++m)
#pragma unroll
      for (int r = 0; r < 4; ++r) {
        int t = m*16 + rb + r;
        size_t oi = ((size_t)t*B_ + b)*D_ + n0 + lr;
        float v = acc[m][r];
        short h, l; split1(v, h, l);
        wth[oi] = h; wtl[oi] = l;
      }
  }
}

extern "C" void kernel_launch(void* const* d_in, const int* in_sizes, int n_in,
                              void* d_out, int out_size, void* d_ws, size_t ws_size,
                              hipStream_t stream) {
  const int*   tok   = (const int*)  d_in[0];
  const float* h0    = (const float*)d_in[1];
  const float* c0    = (const float*)d_in[2];
  const float* ctx   = (const float*)d_in[3];
  const float* emb   = (const float*)d_in[5];
  const float* wih[2] = {(const float*)d_in[6],  (const float*)d_in[10]};
  const float* whh[2] = {(const float*)d_in[7],  (const float*)d_in[11]};
  const float* bih[2] = {(const float*)d_in[8],  (const float*)d_in[12]};
  const float* bhh[2] = {(const float*)d_in[9],  (const float*)d_in[13]};
  const float* w_in  = (const float*)d_in[14];
  const float* w_out = (const float*)d_in[15];
  float* outp = (float*)d_out;

  // ---- workspace layout (~89 MB) ----
  char* ws = (char*)d_ws;
#define MB(x) ((size_t)(x) << 20)
  short* x0h = (short*)(ws + MB(0));    // 4 MB each (T*B*D shorts)
  short* x0l = (short*)(ws + MB(4));
  short* x1h = (short*)(ws + MB(8));
  short* x1l = (short*)(ws + MB(12));
  short* x2h = (short*)(ws + MB(16));
  short* x2l = (short*)(ws + MB(20));
  float* xg  = (float*)(ws + MB(24));   // 32 MB fp32 (T,B,4D)
  short* wihh = (short*)(ws + MB(56));  // 8 MB (4D*D shorts)
  short* wihl = (short*)(ws + MB(64));  // 8 MB
  short* whhh = (short*)(ws + MB(72));  // 8 MB (row-permuted)
  short* whhl = (short*)(ws + MB(80));  // 8 MB
  // overlays (lifetimes disjoint):
  short* q_h  = x0h;                    // q hi/lo over x0 (dead after layer0 xg)
  short* q_l  = x0l;
  short* wt_h = x1h;                    // weighted hi/lo over x1 (dead after layer1 xg)
  short* wt_l = x1l;
  short* winh = (short*)(ws + MB(56));  // w_in hi/lo over wih buf (2 MB each)
  short* winl = (short*)(ws + MB(58));
  short* wouth = (short*)(ws + MB(60)); // w_out hi/lo (4 MB each)
  short* woutl = (short*)(ws + MB(64));
  short* cxh = (short*)(ws + MB(72));   // ctx hi/lo over whh buf (8 MB each)
  short* cxl = (short*)(ws + MB(80));
  float* cbuf = (float*)(ws + MB(88));              // 256 KB
  short* hbh  = (short*)(ws + MB(88) + 262144);     // 2 x 128 KB ping-pong hi
  short* hbl  = (short*)(ws + MB(88) + 524288);     // 2 x 128 KB ping-pong lo
#undef MB

  const size_t BD = (size_t)B_*D_;
  const size_t OUT_HN   = (size_t)T_*B_*D_;   // 2097152
  const size_t OUT_CN   = OUT_HN + 2*BD;
  const size_t OUT_ATTN = OUT_CN + 2*BD;

  embed_split<<<2048, 256, 0, stream>>>(tok, emb, x0h, x0l);

  for (int l = 0; l < 2; ++l) {
    const short* xinh = l ? x1h : x0h;
    const short* xinl = l ? x1l : x0l;
    short* xoh = l ? x2h : x1h;
    short* xol = l ? x2l : x1l;
    // split this layer's weights
    split_kernel<<<4096, 256, 0, stream>>>(wih[l], wihh, wihl);
    // xg = x @ wih^T + (bih+bhh)  : M=2048, N=4096, K=1024, fp32 out
    gemm_hl<<<dim3(64, 32), 256, 0, stream>>>(
        xinh, xinl, D_, wihh, wihl, D_, D_,
        nullptr, nullptr, 0, nullptr, nullptr, 0, 0,
        bih[l], bhh[l], xg, nullptr, nullptr, 4*D_, 0);
    split_whh<<<4096, 256, 0, stream>>>(whh[l], whhh, whhl);
    init_state<<<64, 256, 0, stream>>>(h0 + (size_t)l*BD, c0 + (size_t)l*BD,
                                       hbh, hbl, cbuf);
    for (int t = 0; t < T_; ++t) {
      bool last = (t == T_-1);
      lstm_step3<<<256, 512, 0, stream>>>(
          xg, t, whhh, whhl,
          hbh + (size_t)(t & 1)*BD,     hbl + (size_t)(t & 1)*BD,     cbuf,
          hbh + (size_t)((t+1) & 1)*BD, hbl + (size_t)((t+1) & 1)*BD,
          xoh, xol,
          last ? outp + OUT_HN + (size_t)l*BD : nullptr,
          last ? outp + OUT_CN + (size_t)l*BD : nullptr);
    }
  }

  // split attention/projection weights (overlay wih/whh buffers, now dead)
  split_kernel<<<1024, 256, 0, stream>>>(w_in,  winh,  winl);
  split_kernel<<<2048, 256, 0, stream>>>(w_out, wouth, woutl);
  // q = x2 @ w_in^T -> hi/lo (over x0)
  gemm_hl<<<dim3(16, 32), 256, 0, stream>>>(
      x2h, x2l, D_, winh, winl, D_, D_,
      nullptr, nullptr, 0, nullptr, nullptr, 0, 0,
      nullptr, nullptr, nullptr, q_h, q_l, D_, 0);
  split_kernel<<<4096, 256, 0, stream>>>(ctx, cxh, cxl);
  attn2<<<64, 256, 0, stream>>>(q_h, q_l, cxh, cxl, wt_h, wt_l, outp + OUT_ATTN);
  // out = tanh( wt@w_out[:, :D]^T + x2@w_out[:, D:]^T ) -> fp32
  gemm_hl<<<dim3(16, 32), 256, 0, stream>>>(
      wt_h, wt_l, D_, wouth, woutl, 2*D_, D_,
      x2h, x2l, D_, wouth + D_, woutl + D_, 2*D_, D_,
      nullptr, nullptr, outp, nullptr, nullptr, D_, 1);
}

// Round 3
// 1403.844 us; speedup vs baseline: 4.0254x; 1.4488x over previous
//
#include <hip/hip_runtime.h>
#include <math.h>

#define T_ 32
#define B_ 64
#define S_ 64
#define D_ 1024

typedef __attribute__((ext_vector_type(8))) short short8;
typedef __attribute__((ext_vector_type(4))) float floatx4;

__device__ inline short8 ld8s(const short* p){ return *(const short8*)p; }
__device__ inline floatx4 mfma16(short8 a, short8 b, floatx4 c){
  return __builtin_amdgcn_mfma_f32_16x16x32_bf16(a, b, c, 0, 0, 0);
}
__device__ inline float sigm(float x){ return 1.0f/(1.0f+__expf(-x)); }

// async global->LDS, 16 bytes per lane. LDS dest = wave-uniform base + lane*16.
__device__ inline void load_lds16(const short* g, short* l){
  __builtin_amdgcn_global_load_lds(
      (const __attribute__((address_space(1))) unsigned int*)g,
      (__attribute__((address_space(3))) unsigned int*)l, 16, 0, 0);
}

// ---- fp32 <-> bf16-bits helpers ----
__device__ inline short bfbits(float v){
  unsigned u = __builtin_bit_cast(unsigned, v);
  unsigned r = (u + 0x7FFFu + ((u >> 16) & 1u)) >> 16;   // RNE
  return (short)r;
}
__device__ inline float bitsf(short s){
  unsigned u = ((unsigned)(unsigned short)s) << 16;
  return __builtin_bit_cast(float, u);
}
__device__ inline void split1(float v, short& h, short& l){
  h = bfbits(v); l = bfbits(v - bitsf(h));
}
__device__ inline void pack4(const float4& v, unsigned long long ws_unused,
                             uint2& hp, uint2& lp){
  short h0,h1,h2,h3,l0,l1,l2,l3;
  split1(v.x,h0,l0); split1(v.y,h1,l1); split1(v.z,h2,l2); split1(v.w,h3,l3);
  hp.x = (unsigned short)h0 | ((unsigned)(unsigned short)h1 << 16);
  hp.y = (unsigned short)h2 | ((unsigned)(unsigned short)h3 << 16);
  lp.x = (unsigned short)l0 | ((unsigned)(unsigned short)l1 << 16);
  lp.y = (unsigned short)l2 | ((unsigned)(unsigned short)l3 << 16);
}

// ---------------- generic fp32 -> hi/lo bf16 split ----------------
__global__ __launch_bounds__(256) void split_kernel(const float* __restrict__ src,
                                                    short* __restrict__ hi,
                                                    short* __restrict__ lo){
  int i = blockIdx.x*256 + threadIdx.x;   // one float4 per thread; grid = n/4/256
  float4 v = ((const float4*)src)[i];
  uint2 hp, lp; pack4(v, 0, hp, lp);
  ((uint2*)hi)[i] = hp;
  ((uint2*)lo)[i] = lp;
}

// ---- whh split + row permutation: orig row g*D + d  ->  new row (d>>2)*16 + g*4 + (d&3)
__global__ __launch_bounds__(256) void split_whh(const float* __restrict__ src,
                                                 short* __restrict__ hi,
                                                 short* __restrict__ lo){
  int i = blockIdx.x*256 + threadIdx.x;   // 4D*D/4 float4 elems -> 4096 blocks
  int row = i >> 8, c4 = i & 255;         // D/4 = 256 float4 per row
  int g = row >> 10, d = row & 1023;
  int nrow = ((d >> 2) << 4) + (g << 2) + (d & 3);
  float4 v = ((const float4*)src)[i];
  uint2 hp, lp; pack4(v, 0, hp, lp);
  int o = nrow*256 + c4;
  ((uint2*)hi)[o] = hp;
  ((uint2*)lo)[o] = lp;
}

// ---------------- embedding gather + split (padding_idx=0 -> zeros) ----------------
__global__ __launch_bounds__(256) void embed_split(const int* __restrict__ tok,
                                                   const float* __restrict__ emb,
                                                   short* __restrict__ xh,
                                                   short* __restrict__ xl){
  int i = blockIdx.x*256 + threadIdx.x;   // T*B*D/4 = 524288 -> 2048 blocks
  int d4 = i & 255;
  int tb = i >> 8;
  int idx = tok[tb];
  float4 v;
  if (idx == 0) { v.x=v.y=v.z=v.w=0.f; }
  else          { v = ((const float4*)(emb + (size_t)idx*D_))[d4]; }
  uint2 hp, lp; pack4(v, 0, hp, lp);
  ((uint2*)xh)[i] = hp;
  ((uint2*)xl)[i] = lp;
}

// ---------------- LSTM state init: split h0, copy c0 ----------------
__global__ __launch_bounds__(256) void init_state(const float* __restrict__ h0l,
                                                  const float* __restrict__ c0l,
                                                  short* __restrict__ hh, short* __restrict__ hl,
                                                  float* __restrict__ c){
  int i = blockIdx.x*256 + threadIdx.x;   // B*D/4 = 16384 -> 64 blocks
  float4 v = ((const float4*)h0l)[i];
  uint2 hp, lp; pack4(v, 0, hp, lp);
  ((uint2*)hh)[i] = hp;
  ((uint2*)hl)[i] = lp;
  ((float4*)c)[i] = ((const float4*)c0l)[i];
}

// ==== LDS-staged 128x128 GEMM on hi/lo split operands (m97 structure) ====
// C = act( A1@B1^T [+ A2@B2^T] [+ bias] ), A,B K-contiguous rows (B^T layout).
// 256 threads = 4 waves at 2x2; per wave 64x64 = 4x4 fragments of 16x16x32.
// Per K-step: stage Ah/Al/Bh/Bl 128x32 tiles (8 KB each) via global_load_lds(16B),
// 2 barriers, 48 MFMA/wave. Grid is 1-D (nwg % 8 == 0), XCD-swizzled.
__device__ inline void stage_tile(const short* __restrict__ G, int ld, int rowBase,
                                  int k0, short* lds, int wave, int lane){
#pragma unroll
  for (int c = 0; c < 2; ++c){
    int chunk = (wave*2 + c)*64 + lane;     // 16B chunk index in 8 KB tile
    int row = chunk >> 2, kc = chunk & 3;
    const short* src = G + (size_t)(rowBase + row)*ld + k0 + kc*8;
    load_lds16(src, lds + (size_t)(wave*2 + c)*512);
  }
}

__global__ __launch_bounds__(256) void gemm128(
    const short* __restrict__ A1h, const short* __restrict__ A1l, int lda1,
    const short* __restrict__ B1h, const short* __restrict__ B1l, int ldb1, int K1,
    const short* __restrict__ A2h, const short* __restrict__ A2l, int lda2,
    const short* __restrict__ B2h, const short* __restrict__ B2l, int ldb2, int K2,
    const float* __restrict__ bias0, const float* __restrict__ bias1,
    float* __restrict__ Cf, short* __restrict__ Ch, short* __restrict__ Cl,
    int ldc, int act, int nbx)
{
  __shared__ short Ah[128*32];
  __shared__ short Al[128*32];
  __shared__ short Bh[128*32];
  __shared__ short Bl[128*32];

  const int nwg  = gridDim.x;
  const int w0   = blockIdx.x;
  const int wgid = (w0 & 7)*(nwg >> 3) + (w0 >> 3);   // XCD swizzle (nwg%8==0)
  const int bx = wgid % nbx, by = wgid / nbx;
  const int tid = threadIdx.x;
  const int wave = tid >> 6, lane = tid & 63;
  const int lr = lane & 15, qo = lane >> 4;
  const int wm = wave >> 1, wn = wave & 1;
  const int mBase = by*128, nBase = bx*128;

  floatx4 acc[4][4] = {};

  for (int pass = 0; pass < 2; ++pass){
    const short* pAh; const short* pAl; int lda;
    const short* pBh; const short* pBl; int ldb; int K;
    if (pass == 0){ pAh=A1h; pAl=A1l; lda=lda1; pBh=B1h; pBl=B1l; ldb=ldb1; K=K1; }
    else          { if (!A2h) break;
                    pAh=A2h; pAl=A2l; lda=lda2; pBh=B2h; pBl=B2l; ldb=ldb2; K=K2; }
    for (int k0 = 0; k0 < K; k0 += 32){
      stage_tile(pAh, lda, mBase, k0, Ah, wave, lane);
      stage_tile(pAl, lda, mBase, k0, Al, wave, lane);
      stage_tile(pBh, ldb, nBase, k0, Bh, wave, lane);
      stage_tile(pBl, ldb, nBase, k0, Bl, wave, lane);
      __syncthreads();
      short8 afh[4], afl[4], bfh[4], bfl[4];
#pragma unroll
      for (int f = 0; f < 4; ++f){
        int ar = wm*64 + f*16 + lr;
        int br = wn*64 + f*16 + lr;
        afh[f] = *(const short8*)&Ah[ar*32 + qo*8];
        afl[f] = *(const short8*)&Al[ar*32 + qo*8];
        bfh[f] = *(const short8*)&Bh[br*32 + qo*8];
        bfl[f] = *(const short8*)&Bl[br*32 + qo*8];
      }
#pragma unroll
      for (int mf = 0; mf < 4; ++mf)
#pragma unroll
        for (int nf = 0; nf < 4; ++nf){
          acc[mf][nf] = mfma16(afl[mf], bfh[nf], acc[mf][nf]);
          acc[mf][nf] = mfma16(afh[mf], bfl[nf], acc[mf][nf]);
          acc[mf][nf] = mfma16(afh[mf], bfh[nf], acc[mf][nf]);
        }
      __syncthreads();
    }
  }

  const int rb = qo*4;
#pragma unroll
  for (int nf = 0; nf < 4; ++nf){
    int col = nBase + wn*64 + nf*16 + lr;
    float badd = bias0 ? (bias0[col] + bias1[col]) : 0.f;
#pragma unroll
    for (int mf = 0; mf < 4; ++mf)
#pragma unroll
      for (int r = 0; r < 4; ++r){
        int row = mBase + wm*64 + mf*16 + rb + r;
        size_t idx = (size_t)row*ldc + col;
        float v = acc[mf][nf][r] + badd;
        if (act) v = tanhf(v);
        if (Cf) Cf[idx] = v;
        else { short h,l; split1(v,h,l); Ch[idx] = h; Cl[idx] = l; }
      }
  }
}

// ---- one LSTM timestep, fully fused, self-contained per block ----
// grid = 256 blocks x 512 threads (8 waves). Block j owns the 16 permuted whh rows
// [16j,16j+16) = {gate g, d = 4j+u}. Waves 0-3: batch tiles x K[0,512);
// waves 4-7: batch tiles x K[512,1024). Weight slice staged in swizzled LDS once,
// reused by all 8 waves. Elementwise for d in [4j,4j+4) x 64 batches is block-local.
__global__ __launch_bounds__(512) void lstm_step3(
    const float* __restrict__ xg, int t,
    const short* __restrict__ whr_h, const short* __restrict__ whr_l, // permuted rows
    const short* __restrict__ hih, const short* __restrict__ hil,
    float* __restrict__ c,
    short* __restrict__ hoh, short* __restrict__ hol,
    short* __restrict__ xoh, short* __restrict__ xol,
    float* __restrict__ hn_out, float* __restrict__ cn_out)
{
  __shared__ short8 wv_h[16*128];       // 32 KB, row-chunk XOR swizzled
  __shared__ short8 wv_l[16*128];       // 32 KB
  __shared__ float g_lds[2][64][17];    // 8.5 KB (pad 17 vs bank conflicts)
  const int j    = blockIdx.x;
  const int tid  = threadIdx.x;
  const int wave = tid >> 6;
  const int lane = tid & 63;
  const int lr   = lane & 15;
  const int qo   = lane >> 4;

  // stage 16 weight rows (hi+lo) into LDS with chunk XOR swizzle
  {
    const short8* srcH = (const short8*)(whr_h + (size_t)j*16*D_);
    const short8* srcL = (const short8*)(whr_l + (size_t)j*16*D_);
#pragma unroll
    for (int it = 0; it < 4; ++it) {
      int p = it*512 + tid;             // physical LDS chunk
      int row = p >> 7, pc = p & 127;
      int cc = pc ^ (row & 7);          // logical chunk stored at p
      wv_h[p] = srcH[row*128 + cc];
      wv_l[p] = srcL[row*128 + cc];
    }
  }
  __syncthreads();

  // GEMM: wave = (batch tile bt, K half kh)
  const int bt = (wave & 3) * 16;
  const int kh = wave >> 2;
  const short8* ah8 = (const short8*)(hih + (size_t)(bt + lr)*D_);
  const short8* al8 = (const short8*)(hil + (size_t)(bt + lr)*D_);
  const int bswz = lr*128;
  const int bx   = lr & 7;
  floatx4 acc = {};
#pragma unroll 4
  for (int kc = kh*16; kc < kh*16 + 16; ++kc) {
    int cc = kc*4 + qo;
    short8 ahv = ah8[cc];
    short8 alv = al8[cc];
    int bi = bswz + (cc ^ bx);
    short8 bhv = wv_h[bi];
    short8 blv = wv_l[bi];
    acc = mfma16(alv, bhv, acc);
    acc = mfma16(ahv, blv, acc);
    acc = mfma16(ahv, bhv, acc);
  }
  // C layout: lane holds C[batch = bt + qo*4 + r][gaterow = lr]
  int rb = qo*4;
#pragma unroll
  for (int r = 0; r < 4; ++r)
    g_lds[kh][bt + rb + r][lr] = acc[r];
  __syncthreads();

  // elementwise: 256 elements (64 b x 4 u), threads 0..255
  if (tid < 256) {
    int b = tid >> 2, u = tid & 3;
    int d = j*4 + u;
    size_t xb = ((size_t)t*B_ + b)*(4*D_) + d;
    float i_ = sigm (g_lds[0][b][0*4+u] + g_lds[1][b][0*4+u] + xg[xb        ]);
    float f_ = sigm (g_lds[0][b][1*4+u] + g_lds[1][b][1*4+u] + xg[xb +   D_ ]);
    float gg = tanhf(g_lds[0][b][2*4+u] + g_lds[1][b][2*4+u] + xg[xb + 2*D_]);
    float o_ = sigm (g_lds[0][b][3*4+u] + g_lds[1][b][3*4+u] + xg[xb + 3*D_]);
    size_t ci = (size_t)b*D_ + d;
    float cn = f_*c[ci] + i_*gg;
    c[ci] = cn;
    float h = o_*tanhf(cn);
    short hh, hl; split1(h, hh, hl);
    hoh[ci] = hh; hol[ci] = hl;
    size_t xi = ((size_t)t*B_ + b)*D_ + d;
    xoh[xi] = hh; xol[xi] = hl;
    if (hn_out) { hn_out[ci] = h; cn_out[ci] = cn; }
  }
}

// ---------------- attention: one block per batch b ----------------
__global__ __launch_bounds__(256) void attn2(
    const short* __restrict__ qh, const short* __restrict__ ql,   // (T,B,D)
    const short* __restrict__ cxh, const short* __restrict__ cxl, // (S,B,D)
    short* __restrict__ wth, short* __restrict__ wtl,             // (T,B,D)
    float* __restrict__ attn_out)                                 // (B,S) at t=T-1
{
  int b = blockIdx.x;
  __shared__ float sc[32][64];
  __shared__ short at_hi[32][64];
  __shared__ short at_lo[32][64];
  int wave = threadIdx.x >> 6;
  int lane = threadIdx.x & 63;
  int lr = lane & 15;
  int lk = (lane >> 4) * 8;
  int rb = (lane >> 4) * 4;

  // phase 1: scores(32,64) = Q_b(32,1024) @ CtxB(64,1024)^T
  {
    floatx4 acc[2] = {};
    int n0 = wave * 16;
    size_t Bo = ((size_t)(n0 + lr)*B_ + b)*D_ + lk;
    size_t A0 = ((size_t)(0  + lr)*B_ + b)*D_ + lk;
    size_t A1 = ((size_t)(16 + lr)*B_ + b)*D_ + lk;
    for (int k0 = 0; k0 < D_; k0 += 32) {
      short8 bh = ld8s(cxh + Bo + k0);
      short8 bl = ld8s(cxl + Bo + k0);
      short8 a0h = ld8s(qh + A0 + k0), a0l = ld8s(ql + A0 + k0);
      acc[0] = mfma16(a0l, bh, acc[0]);
      acc[0] = mfma16(a0h, bl, acc[0]);
      acc[0] = mfma16(a0h, bh, acc[0]);
      short8 a1h = ld8s(qh + A1 + k0), a1l = ld8s(ql + A1 + k0);
      acc[1] = mfma16(a1l, bh, acc[1]);
      acc[1] = mfma16(a1h, bl, acc[1]);
      acc[1] = mfma16(a1h, bh, acc[1]);
    }
#pragma unroll
    for (int m = 0; m < 2; ++m)
#pragma unroll
      for (int r = 0; r < 4; ++r)
        sc[m*16 + rb + r][n0 + lr] = acc[m][r];
  }
  __syncthreads();

  // softmax over s; threads 0..31 each own one t
  if (threadIdx.x < 32) {
    int t = threadIdx.x;
    float mx = -1e30f;
    for (int s = 0; s < 64; ++s) mx = fmaxf(mx, sc[t][s]);
    float sum = 0.f;
    for (int s = 0; s < 64; ++s) { float v = __expf(sc[t][s] - mx); sum += v; sc[t][s] = v; }
    float inv = 1.f / sum;
    for (int s = 0; s < 64; ++s) {
      float v = sc[t][s] * inv;
      short h, l; split1(v, h, l);
      at_hi[t][s] = h; at_lo[t][s] = l;
      if (t == 31) attn_out[b*64 + s] = v;
    }
  }
  __syncthreads();

  // phase 2: weighted(32,1024) = attn(32,64) @ CtxB(64,1024)
  for (int i = 0; i < 16; ++i) {
    int n0 = (wave + 4*i) * 16;
    floatx4 acc[2] = {};
#pragma unroll
    for (int kk = 0; kk < 2; ++kk) {
      short8 bh, bl;
#pragma unroll
      for (int j = 0; j < 8; ++j) {
        int s = kk*32 + (lane >> 4)*8 + j;
        size_t o = ((size_t)s*B_ + b)*D_ + n0 + lr;
        bh[j] = cxh[o];
        bl[j] = cxl[o];
      }
      short8 a0h = *(const short8*)&at_hi[0  + lr][kk*32 + lk];
      short8 a0l = *(const short8*)&at_lo[0  + lr][kk*32 + lk];
      short8 a1h = *(const short8*)&at_hi[16 + lr][kk*32 + lk];
      short8 a1l = *(const short8*)&at_lo[16 + lr][kk*32 + lk];
      acc[0] = mfma16(a0l, bh, acc[0]);
      acc[0] = mfma16(a0h, bl, acc[0]);
      acc[0] = mfma16(a0h, bh, acc[0]);
      acc[1] = mfma16(a1l, bh, acc[1]);
      acc[1] = mfma16(a1h, bl, acc[1]);
      acc[1] = mfma16(a1h, bh, acc[1]);
    }
#pragma unroll
    for (int m = 0; m < 2; ++m)
#pragma unroll
      for (int r = 0; r < 4; ++r) {
        int t = m*16 + rb + r;
        size_t oi = ((size_t)t*B_ + b)*D_ + n0 + lr;
        float v = acc[m][r];
        short h, l; split1(v, h, l);
        wth[oi] = h; wtl[oi] = l;
      }
  }
}

extern "C" void kernel_launch(void* const* d_in, const int* in_sizes, int n_in,
                              void* d_out, int out_size, void* d_ws, size_t ws_size,
                              hipStream_t stream) {
  const int*   tok   = (const int*)  d_in[0];
  const float* h0    = (const float*)d_in[1];
  const float* c0    = (const float*)d_in[2];
  const float* ctx   = (const float*)d_in[3];
  const float* emb   = (const float*)d_in[5];
  const float* wih[2] = {(const float*)d_in[6],  (const float*)d_in[10]};
  const float* whh[2] = {(const float*)d_in[7],  (const float*)d_in[11]};
  const float* bih[2] = {(const float*)d_in[8],  (const float*)d_in[12]};
  const float* bhh[2] = {(const float*)d_in[9],  (const float*)d_in[13]};
  const float* w_in  = (const float*)d_in[14];
  const float* w_out = (const float*)d_in[15];
  float* outp = (float*)d_out;

  // ---- workspace layout (~89 MB) ----
  char* ws = (char*)d_ws;
#define MB(x) ((size_t)(x) << 20)
  short* x0h = (short*)(ws + MB(0));    // 4 MB each (T*B*D shorts)
  short* x0l = (short*)(ws + MB(4));
  short* x1h = (short*)(ws + MB(8));
  short* x1l = (short*)(ws + MB(12));
  short* x2h = (short*)(ws + MB(16));
  short* x2l = (short*)(ws + MB(20));
  float* xg  = (float*)(ws + MB(24));   // 32 MB fp32 (T,B,4D)
  short* wihh = (short*)(ws + MB(56));  // 8 MB (4D*D shorts)
  short* wihl = (short*)(ws + MB(64));  // 8 MB
  short* whhh = (short*)(ws + MB(72));  // 8 MB (row-permuted)
  short* whhl = (short*)(ws + MB(80));  // 8 MB
  // overlays (lifetimes disjoint):
  short* q_h  = x0h;                    // q hi/lo over x0 (dead after layer0 xg)
  short* q_l  = x0l;
  short* wt_h = x1h;                    // weighted hi/lo over x1 (dead after layer1 xg)
  short* wt_l = x1l;
  short* winh = (short*)(ws + MB(56));  // w_in hi/lo over wih buf (2 MB each)
  short* winl = (short*)(ws + MB(58));
  short* wouth = (short*)(ws + MB(60)); // w_out hi/lo (4 MB each)
  short* woutl = (short*)(ws + MB(64));
  short* cxh = (short*)(ws + MB(72));   // ctx hi/lo over whh buf (8 MB each)
  short* cxl = (short*)(ws + MB(80));
  float* cbuf = (float*)(ws + MB(88));              // 256 KB
  short* hbh  = (short*)(ws + MB(88) + 262144);     // 2 x 128 KB ping-pong hi
  short* hbl  = (short*)(ws + MB(88) + 524288);     // 2 x 128 KB ping-pong lo
#undef MB

  const size_t BD = (size_t)B_*D_;
  const size_t OUT_HN   = (size_t)T_*B_*D_;   // 2097152
  const size_t OUT_CN   = OUT_HN + 2*BD;
  const size_t OUT_ATTN = OUT_CN + 2*BD;

  embed_split<<<2048, 256, 0, stream>>>(tok, emb, x0h, x0l);

  for (int l = 0; l < 2; ++l) {
    const short* xinh = l ? x1h : x0h;
    const short* xinl = l ? x1l : x0l;
    short* xoh = l ? x2h : x1h;
    short* xol = l ? x2l : x1l;
    // split this layer's weights
    split_kernel<<<4096, 256, 0, stream>>>(wih[l], wihh, wihl);
    // xg = x @ wih^T + (bih+bhh)  : M=2048, N=4096, K=1024, fp32 out
    gemm128<<<512, 256, 0, stream>>>(
        xinh, xinl, D_, wihh, wihl, D_, D_,
        nullptr, nullptr, 0, nullptr, nullptr, 0, 0,
        bih[l], bhh[l], xg, nullptr, nullptr, 4*D_, 0, /*nbx=*/32);
    split_whh<<<4096, 256, 0, stream>>>(whh[l], whhh, whhl);
    init_state<<<64, 256, 0, stream>>>(h0 + (size_t)l*BD, c0 + (size_t)l*BD,
                                       hbh, hbl, cbuf);
    for (int t = 0; t < T_; ++t) {
      bool last = (t == T_-1);
      lstm_step3<<<256, 512, 0, stream>>>(
          xg, t, whhh, whhl,
          hbh + (size_t)(t & 1)*BD,     hbl + (size_t)(t & 1)*BD,     cbuf,
          hbh + (size_t)((t+1) & 1)*BD, hbl + (size_t)((t+1) & 1)*BD,
          xoh, xol,
          last ? outp + OUT_HN + (size_t)l*BD : nullptr,
          last ? outp + OUT_CN + (size_t)l*BD : nullptr);
    }
  }

  // split attention/projection weights (overlay wih/whh buffers, now dead)
  split_kernel<<<1024, 256, 0, stream>>>(w_in,  winh,  winl);
  split_kernel<<<2048, 256, 0, stream>>>(w_out, wouth, woutl);
  // q = x2 @ w_in^T -> hi/lo (over x0)
  gemm128<<<128, 256, 0, stream>>>(
      x2h, x2l, D_, winh, winl, D_, D_,
      nullptr, nullptr, 0, nullptr, nullptr, 0, 0,
      nullptr, nullptr, nullptr, q_h, q_l, D_, 0, /*nbx=*/8);
  split_kernel<<<4096, 256, 0, stream>>>(ctx, cxh, cxl);
  attn2<<<64, 256, 0, stream>>>(q_h, q_l, cxh, cxl, wt_h, wt_l, outp + OUT_ATTN);
  // out = tanh( wt@w_out[:, :D]^T + x2@w_out[:, D:]^T ) -> fp32
  gemm128<<<128, 256, 0, stream>>>(
      wt_h, wt_l, D_, wouth, woutl, 2*D_, D_,
      x2h, x2l, D_, wouth + D_, woutl + D_, 2*D_, D_,
      nullptr, nullptr, outp, nullptr, nullptr, D_, 1, /*nbx=*/8);
}